// Round 10
// baseline (327.183 us; speedup 1.0000x reference)
//
#include <hip/hip_runtime.h>
#include <hip/hip_bf16.h>
#include <hip/hip_cooperative_groups.h>

namespace cg = cooperative_groups;

#define B 4
#define N 1024
#define KNN 30
#define MM 8
#define HID 16
#define FD 320
#define OUTC 512
#define BNS 0.9999950000374997f   // 1/sqrt(1+1e-5)

typedef float f32x4 __attribute__((ext_vector_type(4)));
typedef short s16x8 __attribute__((ext_vector_type(8)));

// workspace float offsets
#define OFF_XT16 0        // 65536 floats: xt16[4096][16] (row-padded AoS, 1 line/row)
#define OFF_XTT  65536    // 36864: xtT[9][4096] (SoA for coalesced knn)
#define OFF_SQ   102400   // 4096
#define OFF_CVT  106496   // 81920 float-slots: cvt_bf 512*320 bf16
#define OFF_K2T  188416   // 131072 float-slots: k2t 4*64*1024 bf16
#define OFF_FB   319488   // 655360 float-slots: feats 4096*320 bf16

// LDS pool byte offsets (persistent | phase-overlaid scratch)
#define L_JS    0         // int[16][30]            1920
#define L_SC    1920      // float[4][16][30][8]    61440
#define L_SSUM  63360     // float[4][16][8]        2048
#define L_FT    65408     // bf16[16][336]          10752
#define L_SCR   76160     // scratch start
#define L_TILE  L_SCR             // P0: float[64][65]   16640
#define L_HIST  L_SCR             // P1: uint[8][256]    8192
#define L_WS    L_SCR             // P2: float[1152]     4608
#define L_DIFF  (L_SCR+4608)      // P2: float[8][30][12] 11520
#define L_HWS   L_SCR             // P3: float[1792]
#define L_OWS   (L_SCR+7168)      // P3: float[512]
#define L_OBS   (L_SCR+9216)      // P3: float[32]
#define L_HS    L_SCR             // P4: bf16[16][1040]  33280
#define L_PACC  (L_SCR+33280)     // P4: float[8][16][16] 8192
#define LDS_SZ  117632

__global__ void __launch_bounds__(512, 1) k_fused(
    const float* __restrict__ x, const float* __restrict__ convt_w,
    const float* __restrict__ mats, const float* __restrict__ conv1_w,
    const float* __restrict__ conv1_b, const float* __restrict__ hw,
    const float* __restrict__ ow, const float* __restrict__ ob,
    float* __restrict__ xt16, float* __restrict__ xtT, float* __restrict__ sq,
    __hip_bfloat16* __restrict__ cvt_bf, __hip_bfloat16* __restrict__ k2t_bf,
    __hip_bfloat16* __restrict__ feats_bf, float* __restrict__ out) {
  cg::grid_group grid = cg::this_grid();
  __shared__ __align__(16) char pool[LDS_SZ];
  int* js = (int*)(pool + L_JS);
  float* sc = (float*)(pool + L_SC);
  float* ssum = (float*)(pool + L_SSUM);
  __hip_bfloat16 (*ftile)[336] = (__hip_bfloat16(*)[336])(pool + L_FT);

  int t = threadIdx.x;
  int bid = blockIdx.x;
  int row0 = bid * 16;
  int b = row0 >> 10;
  int w = t >> 6, lane = t & 63;

  // ================= P0: prep =================
  int gid = bid * 512 + t;
  if (gid < B * N) {
    int bb = gid >> 10, n = gid & 1023;
    float s = 0.f;
#pragma unroll
    for (int c = 0; c < 9; c++) {
      float v = x[(bb * 9 + c) * N + n];
      xt16[gid * 16 + c] = v;
      xtT[c * 4096 + gid] = v;
      s = fmaf(v, v, s);
    }
    sq[gid] = s;
  }
  if (gid < B * OUTC) out[gid] = 0.f;
  for (int i = gid; i < 512 * 320; i += 131072)
    cvt_bf[i] = __float2bfloat16(convt_w[i]);
  if (bid < 64) {   // k2t transpose via LDS tile (block-local barriers ok)
    float (*tile)[65] = (float(*)[65])(pool + L_TILE);
    int l = bid >> 4, part = (bid >> 3) & 1, m = bid & 7;
    int tr = t >> 6, tc = t & 63;
    const float* src = mats + l * 65536 + (part * 64) * 512 + m * 64;
#pragma unroll
    for (int it = 0; it < 8; it++) { int c = it * 8 + tr; tile[c][tc] = src[c * 512 + tc]; }
    __syncthreads();
    __hip_bfloat16* dst = k2t_bf + l * 65536 + part * 512 + m * 64;
#pragma unroll
    for (int it = 0; it < 8; it++) { int o = it * 8 + tr; dst[o * 1024 + tc] = __float2bfloat16(tile[tc][o]); }
  }
  grid.sync();

  // ================= P1: knn, wave-local radix select, 2 rows/wave =========
  unsigned int* histw = (unsigned int*)(pool + L_HIST) + w * 256;
  unsigned long long lowmask = (1ull << lane) - 1ull;
  for (int rr = 0; rr < 2; rr++) {
    int rloc = w * 2 + rr;
    int row = row0 + rloc;
    float cx[9];
#pragma unroll
    for (int c = 0; c < 9; c++) cx[c] = xt16[row * 16 + c];
    float sqn = sq[row];
    unsigned key[16];
#pragma unroll
    for (int s = 0; s < 16; s++) {
      int j = s * 64 + lane;
      float dot = 0.f;
#pragma unroll
      for (int c = 0; c < 9; c++) dot = fmaf(cx[c], xtT[c * 4096 + (b << 10) + j], dot);
      float v = 2.0f * dot - sqn - sq[(b << 10) + j];  // ==0 for j==row (same fma order)
      unsigned u = __float_as_uint(v);
      key[s] = u ^ ((unsigned)(((int)u) >> 31) | 0x80000000u);
    }
    unsigned prefix = 0; int need = KNN;
    for (int p = 0; p < 4; p++) {
      int shift = 24 - 8 * p;
#pragma unroll
      for (int i = 0; i < 4; i++) histw[i * 64 + lane] = 0;
      __syncthreads();
      unsigned himask = p ? (0xFFFFFFFFu << (shift + 8)) : 0u;
#pragma unroll
      for (int s = 0; s < 16; s++)
        if ((key[s] & himask) == prefix) atomicAdd(&histw[(key[s] >> shift) & 255], 1u);
      __syncthreads();
      int c0 = histw[4 * lane], c1 = histw[4 * lane + 1];
      int c2 = histw[4 * lane + 2], c3 = histw[4 * lane + 3];
      int lsum = c0 + c1 + c2 + c3, sfx = lsum;
#pragma unroll
      for (int ofs = 1; ofs < 64; ofs <<= 1) {
        int tt2 = __shfl_down(sfx, ofs, 64);
        if (lane + ofs < 64) sfx += tt2;
      }
      int A3 = sfx - lsum, A2 = A3 + c3, A1 = A2 + c2, A0 = A1 + c1;
      unsigned candp = 0; int candn = 0; bool found = false;
      if (A0 < need && need <= A0 + c0) { candp = prefix | ((unsigned)(4 * lane + 0) << shift); candn = need - A0; found = true; }
      if (A1 < need && need <= A1 + c1) { candp = prefix | ((unsigned)(4 * lane + 1) << shift); candn = need - A1; found = true; }
      if (A2 < need && need <= A2 + c2) { candp = prefix | ((unsigned)(4 * lane + 2) << shift); candn = need - A2; found = true; }
      if (A3 < need && need <= A3 + c3) { candp = prefix | ((unsigned)(4 * lane + 3) << shift); candn = need - A3; found = true; }
      unsigned long long fm = __ballot(found);
      int srcl = __ffsll((unsigned long long)fm) - 1;
      prefix = (unsigned)__shfl((int)candp, srcl, 64);
      need = __shfl(candn, srcl, 64);
    }
    unsigned T = prefix;
    int* jrow = js + rloc * KNN;
    int aboveBase = 0;                       // deterministic ballot emission
#pragma unroll
    for (int s = 0; s < 16; s++) {
      unsigned long long mA = __ballot(key[s] > T);
      if (key[s] > T) jrow[aboveBase + __popcll(mA & lowmask)] = s * 64 + lane;
      aboveBase += __popcll(mA);
    }
    int tieBase = 0;                         // ties ascending idx (JAX-stable)
    for (int s = 0; s < 16 && tieBase < need; s++) {
      unsigned long long mT = __ballot(key[s] == T);
      if (key[s] == T) {
        int rk = tieBase + __popcll(mT & lowmask);
        if (rk < need) jrow[aboveBase + rk] = s * 64 + lane;
      }
      tieBase += __popcll(mT);
    }
  }
  __syncthreads();

  // ================= P2: conv1 + max_k =================
  float* wsL = (float*)(pool + L_WS);
  for (int i = t; i < 1152; i += 512) wsL[i] = conv1_w[i];
  __syncthreads();
  {
    float wd[9], wc[9];
#pragma unroll
    for (int c = 0; c < 9; c++) { wd[c] = wsL[lane * 18 + c]; wc[c] = wsL[lane * 18 + 9 + c]; }
    float bias = conv1_b[lane];
    float* diffb = (float*)(pool + L_DIFF) + w * 360;
    for (int rr = 0; rr < 2; rr++) {
      int rloc = w * 2 + rr, row = row0 + rloc;
      float ctr[9];
#pragma unroll
      for (int c = 0; c < 9; c++) ctr[c] = xt16[row * 16 + c];
      if (lane < KNN) {
        int jg = (b << 10) + js[rloc * KNN + lane];
#pragma unroll
        for (int c = 0; c < 9; c++) diffb[lane * 12 + c] = xt16[jg * 16 + c] - ctr[c];
      }
      __syncthreads();
      float cd = 0.f;
#pragma unroll
      for (int c = 0; c < 9; c++) cd = fmaf(ctr[c], wc[c], cd);
      float best = -3.0e38f;
      for (int k = 0; k < KNN; k++) {
        const f32x4* dr = (const f32x4*)&diffb[k * 12];
        f32x4 d0 = dr[0], d1 = dr[1], d2 = dr[2];
        float dd = 0.f;
        dd = fmaf(d0.x, wd[0], dd); dd = fmaf(d0.y, wd[1], dd);
        dd = fmaf(d0.z, wd[2], dd); dd = fmaf(d0.w, wd[3], dd);
        dd = fmaf(d1.x, wd[4], dd); dd = fmaf(d1.y, wd[5], dd);
        dd = fmaf(d1.z, wd[6], dd); dd = fmaf(d1.w, wd[7], dd);
        dd = fmaf(d2.x, wd[8], dd);
        best = fmaxf(best, dd);
      }
      float val = fmaxf((best + cd + bias) * BNS, 0.f);
      __hip_bfloat16 vb = __float2bfloat16(val);
      feats_bf[row * FD + lane] = vb;
      ftile[rloc][lane] = vb;
      __syncthreads();
    }
  }

  // ================= P3: scorenet (all 4 layers) into LDS =================
  {
    float* hws = (float*)(pool + L_HWS);
    float* ows = (float*)(pool + L_OWS);
    float* obs = (float*)(pool + L_OBS);
    for (int i = t; i < 1792; i += 512) hws[i] = hw[i];
    if (t < 512) ows[t] = ow[t];
    if (t < 32) obs[t] = ob[t];
    __syncthreads();
    if (t < 480) {
      int r = t / KNN, k = t - r * KNN;
      int row = row0 + r;
      int jg = (b << 10) + js[r * KNN + k];
      float xv[28]; float d2 = 0.f;
#pragma unroll
      for (int c = 0; c < 9; c++) {
        float nb = xt16[jg * 16 + c], ct = xt16[row * 16 + c], df = nb - ct;
        xv[c] = df; xv[9 + c] = nb; xv[18 + c] = ct;
        d2 = fmaf(df, df, d2);
      }
      xv[27] = sqrtf(d2);
      for (int l = 0; l < 4; l++) {
        float hid[HID];
#pragma unroll
        for (int h = 0; h < HID; h++) {
          float a = 0.f;
#pragma unroll
          for (int c = 0; c < 28; c++) a = fmaf(xv[c], hws[l * 448 + h * 28 + c], a);
          hid[h] = fmaxf(a * BNS, 0.f);
        }
        float lg[MM], mx = -3.0e38f;
#pragma unroll
        for (int m = 0; m < MM; m++) {
          float a = obs[l * 8 + m];
#pragma unroll
          for (int h = 0; h < HID; h++) a = fmaf(hid[h], ows[l * 128 + m * 16 + h], a);
          lg[m] = a; mx = fmaxf(mx, a);
        }
        float s = 0.f;
#pragma unroll
        for (int m = 0; m < MM; m++) { lg[m] = __expf(lg[m] - mx); s += lg[m]; }
        float inv = 1.0f / s;
        float* so = sc + ((l * 16 + r) * KNN + k) * 8;
#pragma unroll
        for (int m = 0; m < MM; m++) so[m] = lg[m] * inv;
      }
    }
    __syncthreads();
    { int l = t >> 7, r = (t >> 3) & 15, m = t & 7;
      float a = 0.f;
      for (int k = 0; k < KNN; k++) a += sc[((l * 16 + r) * KNN + k) * 8 + m];
      ssum[(l * 16 + r) * 8 + m] = a; }
  }
  grid.sync();

  // ================= P4: 4 PAConv layers =================
  __hip_bfloat16 (*Hs)[1040] = (__hip_bfloat16(*)[1040])(pool + L_HS);
  float* pacc = (float*)(pool + L_PACC);
  int lr = lane & 15, lk8 = (lane >> 4) * 8;
  for (int l = 0; l < 4; l++) {
    for (int rr = 0; rr < 2; rr++) {
      int rloc = w * 2 + rr;
      const float* scrow = sc + ((l * 16 + rloc) * KNN) * 8;
      float g[MM] = {};
      for (int k = 0; k < KNN; k++) {
        int jg = (b << 10) + js[rloc * KNN + k];
        float fv = __bfloat162float(feats_bf[jg * FD + l * 64 + lane]);
        const f32x4* s4 = (const f32x4*)(scrow + k * 8);
        f32x4 s0 = s4[0], s1 = s4[1];
        g[0] = fmaf(s0.x, fv, g[0]); g[1] = fmaf(s0.y, fv, g[1]);
        g[2] = fmaf(s0.z, fv, g[2]); g[3] = fmaf(s0.w, fv, g[3]);
        g[4] = fmaf(s1.x, fv, g[4]); g[5] = fmaf(s1.y, fv, g[5]);
        g[6] = fmaf(s1.z, fv, g[6]); g[7] = fmaf(s1.w, fv, g[7]);
      }
      float fn = __bfloat162float(ftile[rloc][l * 64 + lane]);
      const float* su = ssum + (l * 16 + rloc) * 8;
#pragma unroll
      for (int m = 0; m < MM; m++) {
        Hs[rloc][m * 64 + lane] = __float2bfloat16(g[m] - su[m] * fn);
        Hs[rloc][512 + m * 64 + lane] = __float2bfloat16(g[m]);
      }
    }
    __syncthreads();
    {   // K-split GEMM: wave w -> col-tile w&3, K-half w>>2
      int ct = w & 3, kh = w >> 2;
      const short* Ks2 = (const short*)(k2t_bf + l * 65536);
      const short* brow = Ks2 + (ct * 16 + lr) * 1024 + kh * 512 + lk8;
      const short* arow = (const short*)&Hs[lr][kh * 512 + lk8];
      f32x4 acc = {0.f, 0.f, 0.f, 0.f};
#pragma unroll 8
      for (int kk = 0; kk < 16; kk++) {
        s16x8 a = *(const s16x8*)(arow + kk * 32);
        s16x8 bb = *(const s16x8*)(brow + kk * 32);
        acc = __builtin_amdgcn_mfma_f32_16x16x32_bf16(a, bb, acc, 0, 0, 0);
      }
#pragma unroll
      for (int i = 0; i < 4; i++)
        pacc[(w * 16 + (lane >> 4) * 4 + i) * 16 + lr] = acc[i];
    }
    __syncthreads();
    if (w < 4) {
#pragma unroll
      for (int i = 0; i < 4; i++) {
        int ri = (lane >> 4) * 4 + i;
        float v0 = pacc[(w * 16 + ri) * 16 + lr];
        float v1 = pacc[((w + 4) * 16 + ri) * 16 + lr];
        float val = fmaxf((v0 + v1) * BNS, 0.f);
        __hip_bfloat16 vb = __float2bfloat16(val);
        feats_bf[(row0 + ri) * FD + (l + 1) * 64 + w * 16 + lr] = vb;
        ftile[ri][(l + 1) * 64 + w * 16 + lr] = vb;
      }
    }
    if (l < 3) grid.sync(); else __syncthreads();
  }

  // ================= P5: final conv + global max pool =================
  {
    const short* Ws = (const short*)cvt_bf;
#pragma unroll
    for (int tn = 0; tn < 4; tn++) {
      int nb = w * 64 + tn * 16;
      const short* brow = Ws + (nb + lr) * FD + lk8;
      const short* arow = (const short*)&ftile[lr][lk8];
      f32x4 acc = {0.f, 0.f, 0.f, 0.f};
#pragma unroll
      for (int kk = 0; kk < 10; kk++) {
        s16x8 a = *(const s16x8*)(arow + kk * 32);
        s16x8 bb = *(const s16x8*)(brow + kk * 32);
        acc = __builtin_amdgcn_mfma_f32_16x16x32_bf16(a, bb, acc, 0, 0, 0);
      }
      float mx = fmaxf(fmaxf(acc[0], acc[1]), fmaxf(acc[2], acc[3]));
      mx = fmaxf(mx, __shfl_xor(mx, 16, 64));
      mx = fmaxf(mx, __shfl_xor(mx, 32, 64));
      if ((lane >> 4) == 0) {
        float val = fmaxf(mx * BNS, 0.f);
        atomicMax((unsigned int*)out + b * OUTC + nb + lr, __float_as_uint(val));
      }
    }
  }
}

extern "C" void kernel_launch(void* const* d_in, const int* in_sizes, int n_in,
                              void* d_out, int out_size, void* d_ws, size_t ws_size,
                              hipStream_t stream) {
  const float* x       = (const float*)d_in[0];
  const float* conv1_w = (const float*)d_in[3];
  const float* conv1_b = (const float*)d_in[4];
  const float* sn_hw   = (const float*)d_in[5];
  const float* sn_ow   = (const float*)d_in[6];
  const float* sn_ob   = (const float*)d_in[7];
  const float* mats    = (const float*)d_in[8];
  const float* convt_w = (const float*)d_in[9];
  float* out = (float*)d_out;

  float* wsp = (float*)d_ws;
  float* xt16 = wsp + OFF_XT16;
  float* xtT  = wsp + OFF_XTT;
  float* sq   = wsp + OFF_SQ;
  __hip_bfloat16* cvt_bf = (__hip_bfloat16*)(wsp + OFF_CVT);
  __hip_bfloat16* k2t_bf = (__hip_bfloat16*)(wsp + OFF_K2T);
  __hip_bfloat16* feats_bf = (__hip_bfloat16*)(wsp + OFF_FB);

  void* args[] = {(void*)&x, (void*)&convt_w, (void*)&mats, (void*)&conv1_w,
                  (void*)&conv1_b, (void*)&sn_hw, (void*)&sn_ow, (void*)&sn_ob,
                  (void*)&xt16, (void*)&xtT, (void*)&sq, (void*)&cvt_bf,
                  (void*)&k2t_bf, (void*)&feats_bf, (void*)&out};
  hipLaunchCooperativeKernel((void*)k_fused, dim3(256), dim3(512), args, 0, stream);
}

// Round 11
// 192.889 us; speedup vs baseline: 1.6962x; 1.6962x over previous
//
#include <hip/hip_runtime.h>
#include <hip/hip_bf16.h>

#define B 4
#define N 1024
#define KNN 30
#define MM 8
#define HID 16
#define FD 320
#define OUTC 512
#define BNS 0.9999950000374997f   // 1/sqrt(1+1e-5)

typedef float f32x4 __attribute__((ext_vector_type(4)));
typedef short s16x8 __attribute__((ext_vector_type(8)));

// workspace float offsets
#define OFF_XT16 0        // 65536 floats: xt16[4096][16] (1 cache line / row)
#define OFF_XTT  65536    // 36864: xtT[9][4096] (SoA, coalesced knn)
#define OFF_SQ   102400   // 4096
#define OFF_IDX  106496   // 122880 ints
#define OFF_CVT  229376   // cvt bf16 512*320 -> 81920 float slots
#define OFF_K2T  311296   // k2t bf16 4*64*1024 -> 131072 float slots
#define OFF_FB   442368   // feats bf16 4096*320 -> 655360 float slots
#define OFF_SC   1097728  // score: 4*4096*240 floats

// ---------------- prep (+ k2t transpose) ------------------------------------
__global__ void __launch_bounds__(256) k_prep(const float* __restrict__ x,
                                              const float* __restrict__ convt_w,
                                              const float* __restrict__ mats,
                                              float* __restrict__ xt16,
                                              float* __restrict__ xtT,
                                              float* __restrict__ sq,
                                              __hip_bfloat16* __restrict__ cvt_bf,
                                              __hip_bfloat16* __restrict__ k2t_bf,
                                              float* __restrict__ out) {
  __shared__ float tile[64][65];
  if (blockIdx.x < 640) {
    int id = blockIdx.x * 256 + threadIdx.x;
    if (id < B * N) {
      int b = id >> 10, n = id & 1023;
      float s = 0.f;
#pragma unroll
      for (int c = 0; c < 9; c++) {
        float v = x[(b * 9 + c) * N + n];
        xt16[id * 16 + c] = v;
        xtT[c * 4096 + id] = v;
        s = fmaf(v, v, s);
      }
      sq[id] = s;
    }
    if (id < B * OUTC) out[id] = 0.f;
    if (id < 512 * 320) cvt_bf[id] = __float2bfloat16(convt_w[id]);
  } else {
    int blk = blockIdx.x - 640;        // l*16 + part*8 + m
    int l = blk >> 4, part = (blk >> 3) & 1, m = blk & 7;
    int tr = threadIdx.x >> 6, tc = threadIdx.x & 63;
    const float* src = mats + l * 65536 + (part * 64) * 512 + m * 64;
#pragma unroll
    for (int it = 0; it < 16; it++) { int c = it * 4 + tr; tile[c][tc] = src[c * 512 + tc]; }
    __syncthreads();
    __hip_bfloat16* dst = k2t_bf + l * 65536 + part * 512 + m * 64;
#pragma unroll
    for (int it = 0; it < 16; it++) { int o = it * 4 + tr; dst[o * 1024 + tc] = __float2bfloat16(tile[tc][o]); }
  }
}

// ---------------- knn (radix select, coalesced) + conv1 fused ---------------
__global__ void __launch_bounds__(256) k_knnc1(const float* __restrict__ xt16,
                                               const float* __restrict__ xtT,
                                               const float* __restrict__ sq,
                                               const float* __restrict__ w,
                                               const float* __restrict__ bias,
                                               int* __restrict__ idx,
                                               __hip_bfloat16* __restrict__ feats_bf) {
  int t = threadIdx.x;
  int r = t >> 6;
  int lane = t & 63;
  int row = blockIdx.x * 4 + r;
  int b = row >> 10;
  __shared__ unsigned int hist[4][256];
  __shared__ unsigned int bp[4];
  __shared__ int bn[4];
  __shared__ int js_l[4][KNN];
  __shared__ float ws[64 * 18];
  __shared__ __align__(16) float diff_s[4][KNN][12];
  __shared__ float ctr_s[4][9];
  for (int i = t; i < 64 * 18; i += 256) ws[i] = w[i];
  if (t < 36) { int rr = t / 9, c = t - rr * 9; ctr_s[rr][c] = xt16[(blockIdx.x * 4 + rr) * 16 + c]; }
  const float* xtb = xtT + (b << 10);
  float cx[9];
#pragma unroll
  for (int c = 0; c < 9; c++) cx[c] = xt16[row * 16 + c];
  float sqn = sq[row];
  unsigned int key[16];
#pragma unroll
  for (int s = 0; s < 16; s++) {
    int j = s * 64 + lane;
    float dot = 0.f;
#pragma unroll
    for (int c = 0; c < 9; c++) dot = fmaf(cx[c], xtb[c * 4096 + j], dot);
    float v = 2.0f * dot - sqn - sq[(b << 10) + j];   // ==0 for j==row (same fma order)
    unsigned u = __float_as_uint(v);
    key[s] = u ^ ((unsigned)(((int)u) >> 31) | 0x80000000u);   // asc-sortable
  }
  unsigned prefix = 0; int need = KNN;
  for (int p = 0; p < 4; p++) {
    int shift = 24 - 8 * p;
    for (int i = lane; i < 256; i += 64) hist[r][i] = 0;
    __syncthreads();
    unsigned himask = p ? (0xFFFFFFFFu << (shift + 8)) : 0u;
#pragma unroll
    for (int s = 0; s < 16; s++)
      if ((key[s] & himask) == prefix) atomicAdd(&hist[r][(key[s] >> shift) & 255], 1u);
    __syncthreads();
    int c0 = hist[r][4 * lane], c1 = hist[r][4 * lane + 1];
    int c2 = hist[r][4 * lane + 2], c3 = hist[r][4 * lane + 3];
    int lsum = c0 + c1 + c2 + c3, sfx = lsum;
#pragma unroll
    for (int ofs = 1; ofs < 64; ofs <<= 1) {
      int tt = __shfl_down(sfx, ofs, 64);
      if (lane + ofs < 64) sfx += tt;
    }
    int A3 = sfx - lsum, A2 = A3 + c3, A1 = A2 + c2, A0 = A1 + c1;
    if (A0 < need && need <= A0 + c0) { bp[r] = prefix | ((unsigned)(4 * lane + 0) << shift); bn[r] = need - A0; }
    if (A1 < need && need <= A1 + c1) { bp[r] = prefix | ((unsigned)(4 * lane + 1) << shift); bn[r] = need - A1; }
    if (A2 < need && need <= A2 + c2) { bp[r] = prefix | ((unsigned)(4 * lane + 2) << shift); bn[r] = need - A2; }
    if (A3 < need && need <= A3 + c3) { bp[r] = prefix | ((unsigned)(4 * lane + 3) << shift); bn[r] = need - A3; }
    __syncthreads();
    prefix = bp[r]; need = bn[r];
  }
  unsigned T = prefix;
  int* orow = idx + row * KNN;
  unsigned long long lowmask = (1ull << lane) - 1ull;
  int aboveBase = 0;                          // deterministic ballot emission
#pragma unroll
  for (int s = 0; s < 16; s++) {
    unsigned long long mA = __ballot(key[s] > T);
    if (key[s] > T) {
      int slot = aboveBase + __popcll(mA & lowmask);
      orow[slot] = s * 64 + lane;
      js_l[r][slot] = s * 64 + lane;
    }
    aboveBase += __popcll(mA);
  }
  int tieBase = 0;                            // ties ascending idx (JAX-stable)
  for (int s = 0; s < 16 && tieBase < need; s++) {
    unsigned long long mT = __ballot(key[s] == T);
    if (key[s] == T) {
      int rk = tieBase + __popcll(mT & lowmask);
      if (rk < need) {
        orow[aboveBase + rk] = s * 64 + lane;
        js_l[r][aboveBase + rk] = s * 64 + lane;
      }
    }
    tieBase += __popcll(mT);
  }
  __syncthreads();
  // ---- conv1 phase ----
  if (t < 120) {
    int rr = t / KNN, k = t - rr * KNN;
    int jg = (b << 10) + js_l[rr][k];
#pragma unroll
    for (int c = 0; c < 9; c++) diff_s[rr][k][c] = xt16[jg * 16 + c] - ctr_s[rr][c];
  }
  __syncthreads();
  float wd[9];
#pragma unroll
  for (int c = 0; c < 9; c++) wd[c] = ws[lane * 18 + c];
  float cd = 0.f;
#pragma unroll
  for (int c = 0; c < 9; c++) cd = fmaf(ctr_s[r][c], ws[lane * 18 + 9 + c], cd);
  float best = -3.0e38f;
  for (int k = 0; k < KNN; k++) {
    const f32x4* dr = (const f32x4*)diff_s[r][k];
    f32x4 d0 = dr[0], d1 = dr[1], d2 = dr[2];
    float dd = 0.f;
    dd = fmaf(d0.x, wd[0], dd); dd = fmaf(d0.y, wd[1], dd);
    dd = fmaf(d0.z, wd[2], dd); dd = fmaf(d0.w, wd[3], dd);
    dd = fmaf(d1.x, wd[4], dd); dd = fmaf(d1.y, wd[5], dd);
    dd = fmaf(d1.z, wd[6], dd); dd = fmaf(d1.w, wd[7], dd);
    dd = fmaf(d2.x, wd[8], dd);
    best = fmaxf(best, dd);
  }
  float val = (best + cd + bias[lane]) * BNS;
  feats_bf[row * FD + lane] = __float2bfloat16(fmaxf(val, 0.f));
}

// ---------------- scorenet for ALL 4 layers ---------------------------------
__global__ void __launch_bounds__(256) k_score(const float* __restrict__ xt16,
                                               const int* __restrict__ idx,
                                               const float* __restrict__ hw,
                                               const float* __restrict__ ow,
                                               const float* __restrict__ ob,
                                               float* __restrict__ score) {
  __shared__ float hws[4 * 448];
  __shared__ float ows[4 * 128];
  __shared__ float obs[32];
  int t = threadIdx.x;
  for (int i = t; i < 1792; i += 256) hws[i] = hw[i];
  for (int i = t; i < 512; i += 256) ows[i] = ow[i];
  if (t < 32) obs[t] = ob[t];
  __syncthreads();
  int id = blockIdx.x * 256 + t;       // 0..122879
  int row = id / KNN;
  int b = row >> 10;
  int jg = (b << 10) + idx[id];
  const float* xc = xt16 + row * 16;
  const float* xj = xt16 + jg * 16;
  float xv[28];
  float d2 = 0.f;
#pragma unroll
  for (int c = 0; c < 9; c++) {
    float nb = xj[c], ct = xc[c], df = nb - ct;
    xv[c] = df; xv[9 + c] = nb; xv[18 + c] = ct;
    d2 = fmaf(df, df, d2);
  }
  xv[27] = sqrtf(d2);
  for (int l = 0; l < 4; l++) {
    float hid[HID];
#pragma unroll
    for (int h = 0; h < HID; h++) {
      float a = 0.f;
#pragma unroll
      for (int c = 0; c < 28; c++) a = fmaf(xv[c], hws[l * 448 + h * 28 + c], a);
      hid[h] = fmaxf(a * BNS, 0.f);
    }
    float lg[MM], mx = -3.0e38f;
#pragma unroll
    for (int m = 0; m < MM; m++) {
      float a = obs[l * 8 + m];
#pragma unroll
      for (int h = 0; h < HID; h++) a = fmaf(hid[h], ows[l * 128 + m * 16 + h], a);
      lg[m] = a; mx = fmaxf(mx, a);
    }
    float s = 0.f;
#pragma unroll
    for (int m = 0; m < MM; m++) { lg[m] = __expf(lg[m] - mx); s += lg[m]; }
    float inv = 1.0f / s;
    float* so = score + l * 983040 + id * 8;
    *(float4*)so = make_float4(lg[0] * inv, lg[1] * inv, lg[2] * inv, lg[3] * inv);
    *(float4*)(so + 4) = make_float4(lg[4] * inv, lg[5] * inv, lg[6] * inv, lg[7] * inv);
  }
}

// ---------------- layer: g + 8-wave K-split (H @ K2) MFMA; last folds final -
#define HSTR 1048   // Hs row stride bf16: 524 dw ≡ 12 mod 32 -> ~2-way (free)
__global__ void __launch_bounds__(512) k_layer2(const int* __restrict__ idx,
                                                const float* __restrict__ score,
                                                const __hip_bfloat16* __restrict__ k2t_bf,
                                                __hip_bfloat16* __restrict__ feats_bf,
                                                const __hip_bfloat16* __restrict__ cvt_bf,
                                                float* __restrict__ out,
                                                int l, int last) {
  int row0 = blockIdx.x * 16;
  int t = threadIdx.x;
  int b = row0 >> 10;
  __shared__ int js[16][KNN];
  __shared__ float ssum[16][8];
  __shared__ __align__(16) __hip_bfloat16 Hs[16][HSTR];
  __shared__ __align__(16) __hip_bfloat16 ftile[16][336];
  __shared__ float pacc[8][16][16];
  const float* sc_l = score + l * 983040;
  for (int i = t; i < 16 * KNN; i += 512) {
    int r = i / KNN, k = i - r * KNN;
    js[r][k] = (b << 10) + idx[(row0 + r) * KNN + k];
  }
  if (t < 128) {
    int r = t >> 3, m = t & 7;
    float a = 0.f;
    for (int k = 0; k < KNN; k++) a += sc_l[(row0 + r) * 240 + k * 8 + m];
    ssum[r][m] = a;
  }
  __syncthreads();
  int w = t >> 6, lane = t & 63;
#pragma unroll
  for (int rr = 0; rr < 2; rr++) {
    int r = w * 2 + rr;
    int row = row0 + r;
    const float4* srow = (const float4*)(sc_l + row * 240);
    float g[MM] = {};
#pragma unroll
    for (int k = 0; k < KNN; k++) {
      float fv = __bfloat162float(feats_bf[js[r][k] * FD + l * 64 + lane]);
      float4 s0 = srow[2 * k], s1 = srow[2 * k + 1];
      g[0] = fmaf(s0.x, fv, g[0]); g[1] = fmaf(s0.y, fv, g[1]);
      g[2] = fmaf(s0.z, fv, g[2]); g[3] = fmaf(s0.w, fv, g[3]);
      g[4] = fmaf(s1.x, fv, g[4]); g[5] = fmaf(s1.y, fv, g[5]);
      g[6] = fmaf(s1.z, fv, g[6]); g[7] = fmaf(s1.w, fv, g[7]);
    }
    float fn = __bfloat162float(feats_bf[row * FD + l * 64 + lane]);
#pragma unroll
    for (int m = 0; m < MM; m++) {
      Hs[r][m * 64 + lane] = __float2bfloat16(g[m] - ssum[r][m] * fn);
      Hs[r][512 + m * 64 + lane] = __float2bfloat16(g[m]);
    }
  }
  if (last) {
    // stage cols 0..255 of our 16 rows into ftile (before GEMM uses ftile)
    const short* Fs = (const short*)feats_bf;
    for (int i = t; i < 512; i += 512) {}
    for (int i = t; i < 512; i += 512) {}
    for (int i = t; i < 512; i += 512) {}
  }
  __syncthreads();
  if (last) {
    const short* Fs = (const short*)feats_bf;
    for (int i = t; i < 512; i += 512) {
      int r = i >> 5, c8 = (i & 31) * 8;
      *(s16x8*)&ftile[r][c8] = *(const s16x8*)(Fs + (row0 + r) * FD + c8);
    }
    __syncthreads();
  }
  int lr = lane & 15, lk8 = (lane >> 4) * 8;
  {   // K-split GEMM: wave w -> col-tile w&3, K-half w>>2
    int ct = w & 3, kh = w >> 2;
    const short* Ks2 = (const short*)(k2t_bf + l * 65536);
    const short* brow = Ks2 + (ct * 16 + lr) * 1024 + kh * 512 + lk8;
    const short* arow = (const short*)&Hs[lr][kh * 512 + lk8];
    f32x4 acc = {0.f, 0.f, 0.f, 0.f};
#pragma unroll 8
    for (int kk = 0; kk < 16; kk++) {
      s16x8 a = *(const s16x8*)(arow + kk * 32);
      s16x8 bb = *(const s16x8*)(brow + kk * 32);
      acc = __builtin_amdgcn_mfma_f32_16x16x32_bf16(a, bb, acc, 0, 0, 0);
    }
#pragma unroll
    for (int i = 0; i < 4; i++)
      pacc[w][(lane >> 4) * 4 + i][lr] = acc[i];
  }
  __syncthreads();
  if (w < 4) {
#pragma unroll
    for (int i = 0; i < 4; i++) {
      int ri = (lane >> 4) * 4 + i;
      float val = fmaxf((pacc[w][ri][lr] + pacc[w + 4][ri][lr]) * BNS, 0.f);
      __hip_bfloat16 vb = __float2bfloat16(val);
      if (!last) {
        feats_bf[(row0 + ri) * FD + (l + 1) * 64 + w * 16 + lr] = vb;
      } else {
        ftile[ri][256 + w * 16 + lr] = vb;
      }
    }
  }
  if (last) {
    __syncthreads();
    const short* Ws = (const short*)cvt_bf;
#pragma unroll
    for (int tn = 0; tn < 4; tn++) {
      int nb = w * 64 + tn * 16;
      const short* brow = Ws + (nb + lr) * FD + lk8;
      const short* arow = (const short*)&ftile[lr][lk8];
      f32x4 acc = {0.f, 0.f, 0.f, 0.f};
#pragma unroll
      for (int kk = 0; kk < 10; kk++) {
        s16x8 a = *(const s16x8*)(arow + kk * 32);
        s16x8 bb = *(const s16x8*)(brow + kk * 32);
        acc = __builtin_amdgcn_mfma_f32_16x16x32_bf16(a, bb, acc, 0, 0, 0);
      }
      float mx = fmaxf(fmaxf(acc[0], acc[1]), fmaxf(acc[2], acc[3]));
      mx = fmaxf(mx, __shfl_xor(mx, 16, 64));
      mx = fmaxf(mx, __shfl_xor(mx, 32, 64));
      if ((lane >> 4) == 0) {
        float val = fmaxf(mx * BNS, 0.f);
        atomicMax((unsigned int*)out + b * OUTC + nb + lr, __float_as_uint(val));
      }
    }
  }
}

extern "C" void kernel_launch(void* const* d_in, const int* in_sizes, int n_in,
                              void* d_out, int out_size, void* d_ws, size_t ws_size,
                              hipStream_t stream) {
  const float* x       = (const float*)d_in[0];
  const float* conv1_w = (const float*)d_in[3];
  const float* conv1_b = (const float*)d_in[4];
  const float* sn_hw   = (const float*)d_in[5];
  const float* sn_ow   = (const float*)d_in[6];
  const float* sn_ob   = (const float*)d_in[7];
  const float* mats    = (const float*)d_in[8];
  const float* convt_w = (const float*)d_in[9];
  float* out = (float*)d_out;

  float* wsp = (float*)d_ws;
  float* xt16 = wsp + OFF_XT16;
  float* xtT  = wsp + OFF_XTT;
  float* sq   = wsp + OFF_SQ;
  int* idx    = (int*)(wsp + OFF_IDX);
  __hip_bfloat16* cvt_bf = (__hip_bfloat16*)(wsp + OFF_CVT);
  __hip_bfloat16* k2t_bf = (__hip_bfloat16*)(wsp + OFF_K2T);
  __hip_bfloat16* feats_bf = (__hip_bfloat16*)(wsp + OFF_FB);
  float* score = wsp + OFF_SC;

  k_prep<<<704, 256, 0, stream>>>(x, convt_w, mats, xt16, xtT, sq, cvt_bf, k2t_bf, out);
  k_knnc1<<<1024, 256, 0, stream>>>(xt16, xtT, sq, conv1_w, conv1_b, idx, feats_bf);
  k_score<<<480, 256, 0, stream>>>(xt16, idx, sn_hw, sn_ow, sn_ob, score);
  for (int l = 0; l < 4; l++) {
    k_layer2<<<256, 512, 0, stream>>>(idx, score, k2t_bf, feats_bf, cvt_bf, out,
                                      l, l == 3 ? 1 : 0);
  }
}

// Round 12
// 186.953 us; speedup vs baseline: 1.7501x; 1.0318x over previous
//
#include <hip/hip_runtime.h>
#include <hip/hip_bf16.h>

#define B 4
#define N 1024
#define KNN 30
#define MM 8
#define HID 16
#define FD 320
#define OUTC 512
#define BNS 0.9999950000374997f   // 1/sqrt(1+1e-5)

typedef float f32x4 __attribute__((ext_vector_type(4)));
typedef short s16x8 __attribute__((ext_vector_type(8)));

// workspace float offsets
#define OFF_IDX  0        // 122880 ints
#define OFF_CVT  122880   // cvt bf16 512*320 -> 81920 float slots
#define OFF_K2T  204800   // k2t bf16 4*64*1024 -> 131072 float slots
#define OFF_FB   335872   // feats bf16 4096*320 -> 655360 float slots
#define OFF_SC   991232   // score: 4*4096*240 floats
#define OFF_SSUM 4923392  // ssum: 4*4096*8 floats

// ---------------- prep: k2t transpose + cvt + out zero ----------------------
__global__ void __launch_bounds__(256) k_prep2(const float* __restrict__ mats,
                                               const float* __restrict__ convt_w,
                                               __hip_bfloat16* __restrict__ k2t_bf,
                                               __hip_bfloat16* __restrict__ cvt_bf,
                                               float* __restrict__ out) {
  __shared__ float tile[64][65];
  int t = threadIdx.x;
  if (blockIdx.x < 64) {
    int blk = blockIdx.x;              // l*16 + part*8 + m
    int l = blk >> 4, part = (blk >> 3) & 1, m = blk & 7;
    int tr = t >> 6, tc = t & 63;
    const float* src = mats + l * 65536 + (part * 64) * 512 + m * 64;
#pragma unroll
    for (int it = 0; it < 16; it++) { int c = it * 4 + tr; tile[c][tc] = src[c * 512 + tc]; }
    __syncthreads();
    __hip_bfloat16* dst = k2t_bf + l * 65536 + part * 512 + m * 64;
#pragma unroll
    for (int it = 0; it < 16; it++) { int o = it * 4 + tr; dst[o * 1024 + tc] = __float2bfloat16(tile[tc][o]); }
  } else {
    int id = (blockIdx.x - 64) * 256 + t;    // 0..40959
#pragma unroll
    for (int q = 0; q < 4; q++) {
      int i = id + q * 40960;
      cvt_bf[i] = __float2bfloat16(convt_w[i]);
    }
    if (id < B * OUTC) out[id] = 0.f;
  }
}

// ---------------- k1: knn (radix) + conv1 + scorenet(4 layers) + ssum -------
// x is already SoA per batch: x[b][c][n] -> coalesced distance loads.
__global__ void __launch_bounds__(256) k1(const float* __restrict__ x,
                                          const float* __restrict__ conv1_w,
                                          const float* __restrict__ conv1_b,
                                          const float* __restrict__ hw,
                                          const float* __restrict__ ow,
                                          const float* __restrict__ ob,
                                          int* __restrict__ idx,
                                          __hip_bfloat16* __restrict__ feats_bf,
                                          float* __restrict__ score,
                                          float* __restrict__ ssum_g) {
  int t = threadIdx.x;
  int r = t >> 6, lane = t & 63;
  int row = blockIdx.x * 4 + r;
  int b = row >> 10;
  __shared__ unsigned int hist[4][256];
  __shared__ unsigned int bp[4];
  __shared__ int bn[4];
  __shared__ int js_l[4][KNN];
  __shared__ float ws[1152];
  __shared__ float hws[1792], ows[512], obs[32];
  __shared__ __align__(16) float diff_s[4][KNN][12];
  __shared__ __align__(16) float nbr_s[4][KNN][12];
  __shared__ float ctr_s[4][9];
  __shared__ float scl[4][KNN][8];
  const float* xb = x + b * 9216;    // xb[c*1024 + j]

  for (int i = t; i < 1152; i += 256) ws[i] = conv1_w[i];
  for (int i = t; i < 1792; i += 256) hws[i] = hw[i];
  if (t < 512) { } // (ows loaded below to keep stride-256 loops uniform)
  for (int i = t; i < 512; i += 256) ows[i] = ow[i];
  if (t < 32) obs[t] = ob[t];
  if (t < 36) { int rr = t / 9, c = t - rr * 9; ctr_s[rr][c] = xb[c * 1024 + ((blockIdx.x * 4 + rr) & 1023)]; }

  // ---- distances (sq on the fly; self is exactly 0: identical fma chains) --
  int jrow = row & 1023;
  float cx[9];
#pragma unroll
  for (int c = 0; c < 9; c++) cx[c] = xb[c * 1024 + jrow];
  float sqn = 0.f;
#pragma unroll
  for (int c = 0; c < 9; c++) sqn = fmaf(cx[c], cx[c], sqn);
  unsigned int key[16];
#pragma unroll
  for (int s = 0; s < 16; s++) {
    int j = s * 64 + lane;
    float dot = 0.f, sbj = 0.f;
#pragma unroll
    for (int c = 0; c < 9; c++) {
      float xjc = xb[c * 1024 + j];
      dot = fmaf(cx[c], xjc, dot);
      sbj = fmaf(xjc, xjc, sbj);
    }
    float v = 2.0f * dot - sqn - sbj;
    unsigned u = __float_as_uint(v);
    key[s] = u ^ ((unsigned)(((int)u) >> 31) | 0x80000000u);   // asc-sortable
  }
  // ---- exact top-30 radix select --------------------------------------------
  unsigned prefix = 0; int need = KNN;
  for (int p = 0; p < 4; p++) {
    int shift = 24 - 8 * p;
    for (int i = lane; i < 256; i += 64) hist[r][i] = 0;
    __syncthreads();
    unsigned himask = p ? (0xFFFFFFFFu << (shift + 8)) : 0u;
#pragma unroll
    for (int s = 0; s < 16; s++)
      if ((key[s] & himask) == prefix) atomicAdd(&hist[r][(key[s] >> shift) & 255], 1u);
    __syncthreads();
    int c0 = hist[r][4 * lane], c1 = hist[r][4 * lane + 1];
    int c2 = hist[r][4 * lane + 2], c3 = hist[r][4 * lane + 3];
    int lsum = c0 + c1 + c2 + c3, sfx = lsum;
#pragma unroll
    for (int ofs = 1; ofs < 64; ofs <<= 1) {
      int tt = __shfl_down(sfx, ofs, 64);
      if (lane + ofs < 64) sfx += tt;
    }
    int A3 = sfx - lsum, A2 = A3 + c3, A1 = A2 + c2, A0 = A1 + c1;
    if (A0 < need && need <= A0 + c0) { bp[r] = prefix | ((unsigned)(4 * lane + 0) << shift); bn[r] = need - A0; }
    if (A1 < need && need <= A1 + c1) { bp[r] = prefix | ((unsigned)(4 * lane + 1) << shift); bn[r] = need - A1; }
    if (A2 < need && need <= A2 + c2) { bp[r] = prefix | ((unsigned)(4 * lane + 2) << shift); bn[r] = need - A2; }
    if (A3 < need && need <= A3 + c3) { bp[r] = prefix | ((unsigned)(4 * lane + 3) << shift); bn[r] = need - A3; }
    __syncthreads();
    prefix = bp[r]; need = bn[r];
  }
  unsigned T = prefix;
  int* orow = idx + row * KNN;
  unsigned long long lowmask = (1ull << lane) - 1ull;
  int aboveBase = 0;                          // deterministic ballot emission
#pragma unroll
  for (int s = 0; s < 16; s++) {
    unsigned long long mA = __ballot(key[s] > T);
    if (key[s] > T) {
      int slot = aboveBase + __popcll(mA & lowmask);
      orow[slot] = s * 64 + lane;
      js_l[r][slot] = s * 64 + lane;
    }
    aboveBase += __popcll(mA);
  }
  int tieBase = 0;                            // ties ascending idx (JAX-stable)
  for (int s = 0; s < 16 && tieBase < need; s++) {
    unsigned long long mT = __ballot(key[s] == T);
    if (key[s] == T) {
      int rk = tieBase + __popcll(mT & lowmask);
      if (rk < need) {
        orow[aboveBase + rk] = s * 64 + lane;
        js_l[r][aboveBase + rk] = s * 64 + lane;
      }
    }
    tieBase += __popcll(mT);
  }
  __syncthreads();

  // ---- neighbor staging (exact nbr + diff) ---------------------------------
  if (t < 120) {
    int rr = t / KNN, k = t - rr * KNN;
    int j = js_l[rr][k];
#pragma unroll
    for (int c = 0; c < 9; c++) {
      float nb = xb[c * 1024 + j];
      nbr_s[rr][k][c] = nb;
      diff_s[rr][k][c] = nb - ctr_s[rr][c];
    }
  }
  __syncthreads();

  // ---- conv1 + max_k -------------------------------------------------------
  {
    float wd[9];
#pragma unroll
    for (int c = 0; c < 9; c++) wd[c] = ws[lane * 18 + c];
    float cd = 0.f;
#pragma unroll
    for (int c = 0; c < 9; c++) cd = fmaf(ctr_s[r][c], ws[lane * 18 + 9 + c], cd);
    float best = -3.0e38f;
    for (int k = 0; k < KNN; k++) {
      const f32x4* dr = (const f32x4*)diff_s[r][k];
      f32x4 d0 = dr[0], d1 = dr[1], d2 = dr[2];
      float dd = 0.f;
      dd = fmaf(d0.x, wd[0], dd); dd = fmaf(d0.y, wd[1], dd);
      dd = fmaf(d0.z, wd[2], dd); dd = fmaf(d0.w, wd[3], dd);
      dd = fmaf(d1.x, wd[4], dd); dd = fmaf(d1.y, wd[5], dd);
      dd = fmaf(d1.z, wd[6], dd); dd = fmaf(d1.w, wd[7], dd);
      dd = fmaf(d2.x, wd[8], dd);
      best = fmaxf(best, dd);
    }
    float val = (best + cd + conv1_b[lane]) * BNS;
    feats_bf[row * FD + lane] = __float2bfloat16(fmaxf(val, 0.f));
  }

  // ---- scorenet (4 layers) + ssum ------------------------------------------
  float xv[28];
  int rrS = 0, kS = 0;
  if (t < 120) {
    rrS = t / KNN; kS = t - rrS * KNN;
    float d2 = 0.f;
#pragma unroll
    for (int c = 0; c < 9; c++) {
      float df = diff_s[rrS][kS][c];
      xv[c] = df; xv[9 + c] = nbr_s[rrS][kS][c]; xv[18 + c] = ctr_s[rrS][c];
      d2 = fmaf(df, df, d2);
    }
    xv[27] = sqrtf(d2);
  }
  for (int l = 0; l < 4; l++) {
    if (t < 120) {
      float hid[HID];
#pragma unroll
      for (int h = 0; h < HID; h++) {
        float a = 0.f;
#pragma unroll
        for (int c = 0; c < 28; c++) a = fmaf(xv[c], hws[l * 448 + h * 28 + c], a);
        hid[h] = fmaxf(a * BNS, 0.f);
      }
      float lg[MM], mx = -3.0e38f;
#pragma unroll
      for (int m = 0; m < MM; m++) {
        float a = obs[l * 8 + m];
#pragma unroll
        for (int h = 0; h < HID; h++) a = fmaf(hid[h], ows[l * 128 + m * 16 + h], a);
        lg[m] = a; mx = fmaxf(mx, a);
      }
      float s = 0.f;
#pragma unroll
      for (int m = 0; m < MM; m++) { lg[m] = __expf(lg[m] - mx); s += lg[m]; }
      float inv = 1.0f / s;
      int rowr = blockIdx.x * 4 + rrS;
      float* so = score + l * 983040 + (rowr * KNN + kS) * 8;
      float sv0 = lg[0] * inv, sv1 = lg[1] * inv, sv2 = lg[2] * inv, sv3 = lg[3] * inv;
      float sv4 = lg[4] * inv, sv5 = lg[5] * inv, sv6 = lg[6] * inv, sv7 = lg[7] * inv;
      *(float4*)so = make_float4(sv0, sv1, sv2, sv3);
      *(float4*)(so + 4) = make_float4(sv4, sv5, sv6, sv7);
      scl[rrS][kS][0] = sv0; scl[rrS][kS][1] = sv1; scl[rrS][kS][2] = sv2; scl[rrS][kS][3] = sv3;
      scl[rrS][kS][4] = sv4; scl[rrS][kS][5] = sv5; scl[rrS][kS][6] = sv6; scl[rrS][kS][7] = sv7;
    }
    __syncthreads();
    if (t < 32) {
      int rr = t >> 3, m = t & 7;
      float a = 0.f;
#pragma unroll
      for (int k = 0; k < KNN; k++) a += scl[rr][k][m];
      ssum_g[l * 32768 + (blockIdx.x * 4 + rr) * 8 + m] = a;
    }
    __syncthreads();
  }
}

// ---------------- layer: g + 8-wave K-split (H @ K2) MFMA; last folds final -
#define HSTR 1048   // Hs row stride bf16: 524 dw ≡ 12 mod 32 -> ~2-way (free)
__global__ void __launch_bounds__(512) k_layer2(const int* __restrict__ idx,
                                                const float* __restrict__ score,
                                                const float* __restrict__ ssum_g,
                                                const __hip_bfloat16* __restrict__ k2t_bf,
                                                __hip_bfloat16* __restrict__ feats_bf,
                                                const __hip_bfloat16* __restrict__ cvt_bf,
                                                float* __restrict__ out,
                                                int l, int last) {
  int row0 = blockIdx.x * 16;
  int t = threadIdx.x;
  int b = row0 >> 10;
  __shared__ int js[16][KNN];
  __shared__ float ssum[16][8];
  __shared__ __align__(16) __hip_bfloat16 Hs[16][HSTR];
  __shared__ __align__(16) __hip_bfloat16 ftile[16][336];
  __shared__ float pacc[8][16][16];
  const float* sc_l = score + l * 983040;
  for (int i = t; i < 16 * KNN; i += 512) {
    int r = i / KNN, k = i - r * KNN;
    js[r][k] = (b << 10) + idx[(row0 + r) * KNN + k];
  }
  if (t < 128) ssum[t >> 3][t & 7] = ssum_g[l * 32768 + (row0 + (t >> 3)) * 8 + (t & 7)];
  __syncthreads();
  int w = t >> 6, lane = t & 63;
#pragma unroll
  for (int rr = 0; rr < 2; rr++) {
    int r = w * 2 + rr;
    int row = row0 + r;
    const float4* srow = (const float4*)(sc_l + row * 240);
    float g[MM] = {};
#pragma unroll
    for (int k = 0; k < KNN; k++) {
      float fv = __bfloat162float(feats_bf[js[r][k] * FD + l * 64 + lane]);
      float4 s0 = srow[2 * k], s1 = srow[2 * k + 1];
      g[0] = fmaf(s0.x, fv, g[0]); g[1] = fmaf(s0.y, fv, g[1]);
      g[2] = fmaf(s0.z, fv, g[2]); g[3] = fmaf(s0.w, fv, g[3]);
      g[4] = fmaf(s1.x, fv, g[4]); g[5] = fmaf(s1.y, fv, g[5]);
      g[6] = fmaf(s1.z, fv, g[6]); g[7] = fmaf(s1.w, fv, g[7]);
    }
    float fn = __bfloat162float(feats_bf[row * FD + l * 64 + lane]);
#pragma unroll
    for (int m = 0; m < MM; m++) {
      Hs[r][m * 64 + lane] = __float2bfloat16(g[m] - ssum[r][m] * fn);
      Hs[r][512 + m * 64 + lane] = __float2bfloat16(g[m]);
    }
  }
  __syncthreads();
  if (last) {
    const short* Fs = (const short*)feats_bf;
    {
      int r = t >> 5, c8 = (t & 31) * 8;
      *(s16x8*)&ftile[r][c8] = *(const s16x8*)(Fs + (row0 + r) * FD + c8);
    }
    __syncthreads();
  }
  int lr = lane & 15, lk8 = (lane >> 4) * 8;
  {   // K-split GEMM: wave w -> col-tile w&3, K-half w>>2
    int ct = w & 3, kh = w >> 2;
    const short* Ks2 = (const short*)(k2t_bf + l * 65536);
    const short* brow = Ks2 + (ct * 16 + lr) * 1024 + kh * 512 + lk8;
    const short* arow = (const short*)&Hs[lr][kh * 512 + lk8];
    f32x4 acc = {0.f, 0.f, 0.f, 0.f};
#pragma unroll 8
    for (int kk = 0; kk < 16; kk++) {
      s16x8 a = *(const s16x8*)(arow + kk * 32);
      s16x8 bb = *(const s16x8*)(brow + kk * 32);
      acc = __builtin_amdgcn_mfma_f32_16x16x32_bf16(a, bb, acc, 0, 0, 0);
    }
#pragma unroll
    for (int i = 0; i < 4; i++)
      pacc[w][(lane >> 4) * 4 + i][lr] = acc[i];
  }
  __syncthreads();
  if (w < 4) {
#pragma unroll
    for (int i = 0; i < 4; i++) {
      int ri = (lane >> 4) * 4 + i;
      float val = fmaxf((pacc[w][ri][lr] + pacc[w + 4][ri][lr]) * BNS, 0.f);
      __hip_bfloat16 vb = __float2bfloat16(val);
      if (!last) {
        feats_bf[(row0 + ri) * FD + (l + 1) * 64 + w * 16 + lr] = vb;
      } else {
        ftile[ri][256 + w * 16 + lr] = vb;
      }
    }
  }
  if (last) {
    __syncthreads();
    const short* Ws = (const short*)cvt_bf;
#pragma unroll
    for (int tn = 0; tn < 4; tn++) {
      int nb = w * 64 + tn * 16;
      const short* brow = Ws + (nb + lr) * FD + lk8;
      const short* arow = (const short*)&ftile[lr][lk8];
      f32x4 acc = {0.f, 0.f, 0.f, 0.f};
#pragma unroll
      for (int kk = 0; kk < 10; kk++) {
        s16x8 a = *(const s16x8*)(arow + kk * 32);
        s16x8 bb = *(const s16x8*)(brow + kk * 32);
        acc = __builtin_amdgcn_mfma_f32_16x16x32_bf16(a, bb, acc, 0, 0, 0);
      }
      float mx = fmaxf(fmaxf(acc[0], acc[1]), fmaxf(acc[2], acc[3]));
      mx = fmaxf(mx, __shfl_xor(mx, 16, 64));
      mx = fmaxf(mx, __shfl_xor(mx, 32, 64));
      if ((lane >> 4) == 0) {
        float val = fmaxf(mx * BNS, 0.f);
        atomicMax((unsigned int*)out + b * OUTC + nb + lr, __float_as_uint(val));
      }
    }
  }
}

extern "C" void kernel_launch(void* const* d_in, const int* in_sizes, int n_in,
                              void* d_out, int out_size, void* d_ws, size_t ws_size,
                              hipStream_t stream) {
  const float* x       = (const float*)d_in[0];
  const float* conv1_w = (const float*)d_in[3];
  const float* conv1_b = (const float*)d_in[4];
  const float* sn_hw   = (const float*)d_in[5];
  const float* sn_ow   = (const float*)d_in[6];
  const float* sn_ob   = (const float*)d_in[7];
  const float* mats    = (const float*)d_in[8];
  const float* convt_w = (const float*)d_in[9];
  float* out = (float*)d_out;

  float* wsp = (float*)d_ws;
  int* idx    = (int*)(wsp + OFF_IDX);
  __hip_bfloat16* cvt_bf = (__hip_bfloat16*)(wsp + OFF_CVT);
  __hip_bfloat16* k2t_bf = (__hip_bfloat16*)(wsp + OFF_K2T);
  __hip_bfloat16* feats_bf = (__hip_bfloat16*)(wsp + OFF_FB);
  float* score = wsp + OFF_SC;
  float* ssum_g = wsp + OFF_SSUM;

  k_prep2<<<224, 256, 0, stream>>>(mats, convt_w, k2t_bf, cvt_bf, out);
  k1<<<1024, 256, 0, stream>>>(x, conv1_w, conv1_b, sn_hw, sn_ow, sn_ob,
                               idx, feats_bf, score, ssum_g);
  for (int l = 0; l < 4; l++) {
    k_layer2<<<256, 512, 0, stream>>>(idx, score, ssum_g, k2t_bf, feats_bf,
                                      cvt_bf, out, l, l == 3 ? 1 : 0);
  }
}